// Round 1
// baseline (170.394 us; speedup 1.0000x reference)
//
#include <hip/hip_runtime.h>

namespace {

constexpr int T_LEN = 512;

// ds_swizzle with compile-time pattern (BitMode: offset = xor<<10 | or<<5 | and)
template<int OFF>
__device__ __forceinline__ float ds_swz(float v) {
    return __builtin_bit_cast(float,
        __builtin_amdgcn_ds_swizzle(__builtin_bit_cast(int, v), OFF));
}

// broadcast lane K (0..15) within each 16-lane group: src = (lane & 0x10) | K
template<int K>
__device__ __forceinline__ float bcast16(float v) {
    return ds_swz<(K << 5) | 0x10>(v);
}

__device__ __forceinline__ float fast_sigmoid(float a) {
    // 1 / (1 + e^-a)
    return __builtin_amdgcn_rcpf(1.0f + __expf(-a));
}
__device__ __forceinline__ float fast_tanh(float a) {
    // tanh(a) = 1 - 2/(e^{2a}+1)
    return __builtin_fmaf(-2.0f, __builtin_amdgcn_rcpf(1.0f + __expf(2.0f * a)), 1.0f);
}

// accumulate gh_{r,z,n} over all 16 h entries (h[k] broadcast from lane k)
template<int K>
__device__ __forceinline__ void hgather(float h,
        const float (&wr)[16], const float (&wz)[16], const float (&wn)[16],
        float& gr, float& gz, float& gn) {
    float hk = bcast16<K>(h);
    gr = __builtin_fmaf(hk, wr[K], gr);
    gz = __builtin_fmaf(hk, wz[K], gz);
    gn = __builtin_fmaf(hk, wn[K], gn);
    if constexpr (K < 15) hgather<K + 1>(h, wr, wz, wn, gr, gz, gn);
}

// 16 GRU steps; x for step K comes from lane K's xv register
template<int K>
__device__ __forceinline__ void do_steps(float& h, float xv,
        const float (&wr)[16], const float (&wz)[16], const float (&wn)[16],
        float wih_r, float wih_z, float wih_n,
        float bias_r, float bias_z, float b_ihn, float b_hhn) {
    float xt = bcast16<K>(xv);
    float gr = __builtin_fmaf(xt, wih_r, bias_r);   // x-proj + (b_ih + b_hh) for r
    float gz = __builtin_fmaf(xt, wih_z, bias_z);   // same for z
    float gn = b_hhn;                               // hn accumulates b_hh only
    hgather<0>(h, wr, wz, wn, gr, gz, gn);
    float r  = fast_sigmoid(gr);
    float z  = fast_sigmoid(gz);
    float xn = __builtin_fmaf(xt, wih_n, b_ihn);
    float n  = fast_tanh(__builtin_fmaf(r, gn, xn));
    h = __builtin_fmaf(z, h - n, n);                // (1-z)*n + z*h
    if constexpr (K < 15)
        do_steps<K + 1>(h, xv, wr, wz, wn, wih_r, wih_z, wih_n,
                        bias_r, bias_z, b_ihn, b_hhn);
}

__global__ __launch_bounds__(256) void gru_fused(
        const float* __restrict__ x,
        const float* __restrict__ W_ih,
        const float* __restrict__ W_hh,
        const float* __restrict__ b_ih,
        const float* __restrict__ b_hh,
        const float* __restrict__ fc_w,
        const float* __restrict__ fc_b,
        float* __restrict__ out, int B) {
    const int tid = blockIdx.x * blockDim.x + threadIdx.x;
    const int b = tid >> 4;       // batch element (16 lanes each)
    const int j = tid & 15;       // hidden index owned by this lane
    if (b >= B) return;

    // Per-lane weights: rows j, j+16, j+32 of W_hh (48x16, row-major)
    float wr[16], wz[16], wn[16];
    const float4* Wr4 = reinterpret_cast<const float4*>(W_hh + j * 16);
    const float4* Wz4 = reinterpret_cast<const float4*>(W_hh + (j + 16) * 16);
    const float4* Wn4 = reinterpret_cast<const float4*>(W_hh + (j + 32) * 16);
#pragma unroll
    for (int q = 0; q < 4; ++q) {
        float4 a = Wr4[q];
        wr[4*q+0] = a.x; wr[4*q+1] = a.y; wr[4*q+2] = a.z; wr[4*q+3] = a.w;
        float4 bb = Wz4[q];
        wz[4*q+0] = bb.x; wz[4*q+1] = bb.y; wz[4*q+2] = bb.z; wz[4*q+3] = bb.w;
        float4 cc = Wn4[q];
        wn[4*q+0] = cc.x; wn[4*q+1] = cc.y; wn[4*q+2] = cc.z; wn[4*q+3] = cc.w;
    }
    const float wih_r = W_ih[j], wih_z = W_ih[j + 16], wih_n = W_ih[j + 32];
    const float bias_r = b_ih[j] + b_hh[j];
    const float bias_z = b_ih[j + 16] + b_hh[j + 16];
    const float b_ihn = b_ih[j + 32];
    const float b_hhn = b_hh[j + 32];

    const float* xb = x + (size_t)b * T_LEN;
    float h = 0.0f;
    float xv = xb[j];                       // 16 timesteps of x, one per lane
#pragma unroll 1
    for (int c = 0; c < T_LEN / 16; ++c) {
        float xnext = 0.0f;
        if (c + 1 < T_LEN / 16) xnext = xb[(c + 1) * 16 + j];   // prefetch
        do_steps<0>(h, xv, wr, wz, wn, wih_r, wih_z, wih_n,
                    bias_r, bias_z, b_ihn, b_hhn);
        xv = xnext;
    }

    // out[b] = sum_j h[j] * fc_w[j] + fc_b  (butterfly reduce within 16 lanes)
    float p = h * fc_w[j];
    p += ds_swz<0x041F>(p);   // xor 1
    p += ds_swz<0x081F>(p);   // xor 2
    p += ds_swz<0x101F>(p);   // xor 4
    p += ds_swz<0x201F>(p);   // xor 8
    if (j == 0) out[b] = p + fc_b[0];
}

} // namespace

extern "C" void kernel_launch(void* const* d_in, const int* in_sizes, int n_in,
                              void* d_out, int out_size, void* d_ws, size_t ws_size,
                              hipStream_t stream) {
    const float* x    = (const float*)d_in[0];
    const float* W_ih = (const float*)d_in[1];
    const float* W_hh = (const float*)d_in[2];
    const float* b_ih = (const float*)d_in[3];
    const float* b_hh = (const float*)d_in[4];
    const float* fc_w = (const float*)d_in[5];
    const float* fc_b = (const float*)d_in[6];
    float* out = (float*)d_out;

    const int B = out_size;            // 8192
    const int threads = 256;
    const int total = B * 16;          // 16 lanes per batch element
    const int blocks = (total + threads - 1) / threads;
    gru_fused<<<blocks, threads, 0, stream>>>(x, W_ih, W_hh, b_ih, b_hh,
                                              fc_w, fc_b, out, B);
}

// Round 2
// 142.179 us; speedup vs baseline: 1.1984x; 1.1984x over previous
//
#include <hip/hip_runtime.h>

namespace {

constexpr int T_LEN = 512;

// ds_swizzle (epilogue reduction only)
template<int OFF>
__device__ __forceinline__ float ds_swz(float v) {
    return __builtin_bit_cast(float,
        __builtin_amdgcn_ds_swizzle(__builtin_bit_cast(int, v), OFF));
}

// DPP mov with compile-time control. row_ror:N = 0x120|N (rotates within 16-lane row)
template<int CTRL>
__device__ __forceinline__ float dpp_mov(float v) {
    return __builtin_bit_cast(float,
        __builtin_amdgcn_mov_dpp(__builtin_bit_cast(int, v), CTRL, 0xF, 0xF, false));
}

// packed fp32 FMA / MUL (v_pk_*_f32, CDNA packed math — 2 fp32 per instr)
__device__ __forceinline__ void pk_fma(float2& acc, float2 a, float2 b) {
    asm("v_pk_fma_f32 %0, %1, %2, %0" : "+v"(acc) : "v"(a), "v"(b));
}
__device__ __forceinline__ float2 pk_mul(float2 a, float2 b) {
    float2 d;
    asm("v_pk_mul_f32 %0, %1, %2" : "=v"(d) : "v"(a), "v"(b));
    return d;
}

__device__ __forceinline__ float fast_sigmoid(float a) {
    return __builtin_amdgcn_rcpf(1.0f + __expf(-a));
}
__device__ __forceinline__ float fast_tanh(float a) {
    return __builtin_fmaf(-2.0f, __builtin_amdgcn_rcpf(1.0f + __expf(2.0f * a)), 1.0f);
}

// One GRU step. hp chains: hp.x covers k-offsets {0,2,4,...}, hp.y {1,3,...} (×di).
__device__ __forceinline__ void gru_step(float& h, float xt,
        const float2 (&wr)[8], const float2 (&wz)[8], const float2 (&wn)[8],
        float wih_r, float wih_z, float wih_n,
        float bias_r, float bias_z, float b_ihn, float b_hhn) {
    float2 hp;
    hp.x = h;
    hp.y = dpp_mov<0x121>(h);            // ror:1
    float2 ar = pk_mul(hp, wr[0]);
    float2 az = pk_mul(hp, wz[0]);
    float2 an = pk_mul(hp, wn[0]);
#pragma unroll
    for (int i = 1; i < 8; ++i) {
        hp.x = dpp_mov<0x122>(hp.x);     // ror:2
        hp.y = dpp_mov<0x122>(hp.y);
        pk_fma(ar, hp, wr[i]);
        pk_fma(az, hp, wz[i]);
        pk_fma(an, hp, wn[i]);
    }
    float sr = __builtin_fmaf(xt, wih_r, bias_r) + (ar.x + ar.y);
    float sz = __builtin_fmaf(xt, wih_z, bias_z) + (az.x + az.y);
    float r  = fast_sigmoid(sr);
    float z  = fast_sigmoid(sz);
    float hn = (an.x + an.y) + b_hhn;
    float xn = __builtin_fmaf(xt, wih_n, b_ihn);
    float n  = fast_tanh(__builtin_fmaf(r, hn, xn));
    h = __builtin_fmaf(z, h - n, n);     // (1-z)*n + z*h
}

__global__ __launch_bounds__(256) void gru_fused(
        const float* __restrict__ x,
        const float* __restrict__ W_ih,
        const float* __restrict__ W_hh,
        const float* __restrict__ b_ih,
        const float* __restrict__ b_hh,
        const float* __restrict__ fc_w,
        const float* __restrict__ fc_b,
        float* __restrict__ out, int B) {
    const int tid = blockIdx.x * blockDim.x + threadIdx.x;
    const int b = tid >> 4;       // batch element (16 lanes each)
    const int j = tid & 15;       // hidden index owned by this lane
    if (b >= B) return;

    // --- Probe DPP ror direction: after ror:1, lane j holds value from lane (j+d)&15.
    int pr = __builtin_amdgcn_mov_dpp(j, 0x121, 0xF, 0xF, false);
    const int di = (pr - j) & 15;        // d (1 or 15 == -1), uniform across lanes

    // --- Weights, rotation-permuted: iteration pair i uses k = (j + 2i*di)&15 and (j+(2i+1)*di)&15
    const float* Wr = W_hh + j * 16;
    const float* Wz = W_hh + (j + 16) * 16;
    const float* Wn = W_hh + (j + 32) * 16;
    float2 wr[8], wz[8], wn[8];
#pragma unroll
    for (int i = 0; i < 8; ++i) {
        int kx = (j + 2 * i * di) & 15;
        int ky = (j + (2 * i + 1) * di) & 15;
        wr[i] = make_float2(Wr[kx], Wr[ky]);
        wz[i] = make_float2(Wz[kx], Wz[ky]);
        wn[i] = make_float2(Wn[kx], Wn[ky]);
    }
    const float wih_r = W_ih[j], wih_z = W_ih[j + 16], wih_n = W_ih[j + 32];
    const float bias_r = b_ih[j] + b_hh[j];
    const float bias_z = b_ih[j + 16] + b_hh[j + 16];
    const float b_ihn = b_ih[j + 32];
    const float b_hhn = b_hh[j + 32];

    // --- x: all 16 lanes of a group load the same chunk (L1 broadcast), double-buffered
    const float4* xb4 = reinterpret_cast<const float4*>(x + (size_t)b * T_LEN);
    float4 xq0 = xb4[0], xq1 = xb4[1], xq2 = xb4[2], xq3 = xb4[3];

    float h = 0.0f;
#pragma unroll 1
    for (int c = 0; c < T_LEN / 16; ++c) {
        float4 xn0, xn1, xn2, xn3;
        if (c + 1 < T_LEN / 16) {
            xn0 = xb4[(c + 1) * 4 + 0];
            xn1 = xb4[(c + 1) * 4 + 1];
            xn2 = xb4[(c + 1) * 4 + 2];
            xn3 = xb4[(c + 1) * 4 + 3];
        }
#pragma unroll
        for (int s = 0; s < 16; ++s) {
            float4 v = (s < 4) ? xq0 : (s < 8) ? xq1 : (s < 12) ? xq2 : xq3;
            float xt = ((s & 3) == 0) ? v.x : ((s & 3) == 1) ? v.y
                     : ((s & 3) == 2) ? v.z : v.w;
            gru_step(h, xt, wr, wz, wn, wih_r, wih_z, wih_n,
                     bias_r, bias_z, b_ihn, b_hhn);
        }
        if (c + 1 < T_LEN / 16) {
            xq0 = xn0; xq1 = xn1; xq2 = xn2; xq3 = xn3;
        }
    }

    // out[b] = sum_j h[j] * fc_w[j] + fc_b  (butterfly reduce within 16 lanes)
    float p = h * fc_w[j];
    p += ds_swz<0x041F>(p);   // xor 1
    p += ds_swz<0x081F>(p);   // xor 2
    p += ds_swz<0x101F>(p);   // xor 4
    p += ds_swz<0x201F>(p);   // xor 8
    if (j == 0) out[b] = p + fc_b[0];
}

} // namespace

extern "C" void kernel_launch(void* const* d_in, const int* in_sizes, int n_in,
                              void* d_out, int out_size, void* d_ws, size_t ws_size,
                              hipStream_t stream) {
    const float* x    = (const float*)d_in[0];
    const float* W_ih = (const float*)d_in[1];
    const float* W_hh = (const float*)d_in[2];
    const float* b_ih = (const float*)d_in[3];
    const float* b_hh = (const float*)d_in[4];
    const float* fc_w = (const float*)d_in[5];
    const float* fc_b = (const float*)d_in[6];
    float* out = (float*)d_out;

    const int B = out_size;            // 8192
    const int threads = 256;
    const int total = B * 16;          // 16 lanes per batch element
    const int blocks = (total + threads - 1) / threads;
    gru_fused<<<blocks, threads, 0, stream>>>(x, W_ih, W_hh, b_ih, b_hh,
                                              fc_w, fc_b, out, B);
}

// Round 4
// 140.082 us; speedup vs baseline: 1.2164x; 1.0150x over previous
//
#include <hip/hip_runtime.h>

namespace {

constexpr int T_LEN = 512;
constexpr float LOG2E = 1.4426950408889634f;

typedef short v4s __attribute__((ext_vector_type(4)));
typedef float v4f __attribute__((ext_vector_type(4)));

__device__ __forceinline__ float fexp2(float a) {
#if __has_builtin(__builtin_amdgcn_exp2f)
    return __builtin_amdgcn_exp2f(a);
#else
    return exp2f(a);
#endif
}

__device__ __forceinline__ v4f mfma16(v4s a, v4s b, v4f c) {
#if __has_builtin(__builtin_amdgcn_mfma_f32_16x16x16bf16_1k)
    return __builtin_amdgcn_mfma_f32_16x16x16bf16_1k(a, b, c, 0, 0, 0);
#else
    v4f d;
    asm volatile("v_mfma_f32_16x16x16_bf16 %0, %1, %2, %3\n\t"
                 "s_nop 7\n\ts_nop 7"
                 : "=v"(d) : "v"(a), "v"(b), "v"(c));
    return d;
#endif
}

// pack bf16(a) (low 16) and bf16(b) (high 16) into one u32, truncation rounding
__device__ __forceinline__ unsigned pk_bf16_trunc(float a, float b) {
    unsigned ua = __builtin_bit_cast(unsigned, a);
    unsigned ub = __builtin_bit_cast(unsigned, b);
    return (ua >> 16) | (ub & 0xffff0000u);
}
__device__ __forceinline__ float trunc_bf16_f32(float a) {
    return __builtin_bit_cast(float, __builtin_bit_cast(unsigned, a) & 0xffff0000u);
}
__device__ __forceinline__ v4s make_v4s(unsigned lo, unsigned hi) {
    uint2 t = make_uint2(lo, hi);
    return __builtin_bit_cast(v4s, t);
}
// split an f32x4 (already scaled) into hi/lo bf16 fragments
__device__ __forceinline__ void split_frag(float fx, float fy, float fz, float fw,
                                           v4s& fhi, v4s& flo) {
    fhi = make_v4s(pk_bf16_trunc(fx, fy), pk_bf16_trunc(fz, fw));
    float rx = fx - trunc_bf16_f32(fx);
    float ry = fy - trunc_bf16_f32(fy);
    float rz = fz - trunc_bf16_f32(fz);
    float rw = fw - trunc_bf16_f32(fw);
    flo = make_v4s(pk_bf16_trunc(rx, ry), pk_bf16_trunc(rz, rw));
}

__device__ __forceinline__ float sigm2(float d) {   // d = -log2e * preact
    return __builtin_amdgcn_rcpf(1.0f + fexp2(d));
}

__global__ __launch_bounds__(64) void gru_mfma(
        const float* __restrict__ x,
        const float* __restrict__ W_ih,
        const float* __restrict__ W_hh,
        const float* __restrict__ b_ih,
        const float* __restrict__ b_hh,
        const float* __restrict__ fc_w,
        const float* __restrict__ fc_b,
        float* __restrict__ out, int B) {
    const int L  = threadIdx.x;      // 0..63
    const int e  = L & 15;           // element column (D/B col) AND A row
    const int g  = L >> 4;           // k/row group
    const int jD = g * 4;            // D rows / B k-range owned by this lane
    const int be = blockIdx.x * 16 + e;

    const float sR = -LOG2E;         // sigmoid gates: r = rcp(1+exp2(-log2e*a))
    const float sN = 2.0f * LOG2E;   // tanh: n = 1-2*rcp(1+exp2(2*log2e*v))

    // ---- A fragments (W_hh rows = gate output j = e; k = jD..jD+3), scaled+split
    const float4 wr4 = *(const float4*)(W_hh + (0  + e) * 16 + jD);
    const float4 wz4 = *(const float4*)(W_hh + (16 + e) * 16 + jD);
    const float4 wn4 = *(const float4*)(W_hh + (32 + e) * 16 + jD);
    v4s ar_hi, ar_lo, az_hi, az_lo, an_hi, an_lo;
    split_frag(wr4.x * sR, wr4.y * sR, wr4.z * sR, wr4.w * sR, ar_hi, ar_lo);
    split_frag(wz4.x * sR, wz4.y * sR, wz4.z * sR, wz4.w * sR, az_hi, az_lo);
    split_frag(wn4.x * sN, wn4.y * sN, wn4.z * sN, wn4.w * sN, an_hi, an_lo);

    // ---- per-D-row constants (rows jD+i)
    float wihr[4], wihz[4], wihn[4], biasr[4], biasz[4], bihn[4];
    v4f cn_const;
#pragma unroll
    for (int i = 0; i < 4; ++i) {
        int rj = jD + i;
        wihr[i]  = W_ih[rj]        * sR;
        wihz[i]  = W_ih[16 + rj]   * sR;
        wihn[i]  = W_ih[32 + rj]   * sN;
        biasr[i] = (b_ih[rj]      + b_hh[rj])      * sR;
        biasz[i] = (b_ih[16 + rj] + b_hh[16 + rj]) * sR;
        bihn[i]  = b_ih[32 + rj]   * sN;
        cn_const[i] = b_hh[32 + rj] * sN;
    }

    // ---- x: this lane's element's timeline, 16 steps per chunk (4 x float4)
    const float4* xb = (const float4*)(x + (size_t)be * T_LEN);
    float4 xc0 = xb[0], xc1 = xb[1], xc2 = xb[2], xc3 = xb[3];

    float h0 = 0.f, h1 = 0.f, h2 = 0.f, h3 = 0.f;
    v4s bhi = make_v4s(0u, 0u), blo = make_v4s(0u, 0u);

#pragma unroll 1
    for (int c = 0; c < T_LEN / 16; ++c) {
        float4 xn0, xn1, xn2, xn3;
        if (c + 1 < T_LEN / 16) {
            xn0 = xb[(c + 1) * 4 + 0];
            xn1 = xb[(c + 1) * 4 + 1];
            xn2 = xb[(c + 1) * 4 + 2];
            xn3 = xb[(c + 1) * 4 + 3];
        }
#pragma unroll
        for (int s = 0; s < 16; ++s) {
            float4 q4 = (s < 4) ? xc0 : (s < 8) ? xc1 : (s < 12) ? xc2 : xc3;
            float xt  = ((s & 3) == 0) ? q4.x : ((s & 3) == 1) ? q4.y
                      : ((s & 3) == 2) ? q4.z : q4.w;

            // C-inits (x-projection + biases, pre-scaled)
            v4f cr, cz;
#pragma unroll
            for (int i = 0; i < 4; ++i) {
                cr[i] = __builtin_fmaf(xt, wihr[i], biasr[i]);
                cz[i] = __builtin_fmaf(xt, wihz[i], biasz[i]);
            }
            // 3 split-MFMAs per gate: W_hi*h_hi + W_lo*h_hi + W_hi*h_lo
            v4f dr = mfma16(ar_hi, bhi, cr);
            v4f dz = mfma16(az_hi, bhi, cz);
            v4f dn = mfma16(an_hi, bhi, cn_const);
            dr = mfma16(ar_lo, bhi, dr);
            dz = mfma16(az_lo, bhi, dz);
            dn = mfma16(an_lo, bhi, dn);
            dr = mfma16(ar_hi, blo, dr);
            dz = mfma16(az_hi, blo, dz);
            dn = mfma16(an_hi, blo, dn);

            // gates + h update (fp32), 4 hidden units per lane
            {
                float r = sigm2(dr[0]);
                float z = sigm2(dz[0]);
                float xn = __builtin_fmaf(xt, wihn[0], bihn[0]);
                float v  = __builtin_fmaf(r, dn[0], xn);
                float n  = __builtin_fmaf(-2.0f, __builtin_amdgcn_rcpf(1.0f + fexp2(v)), 1.0f);
                h0 = __builtin_fmaf(z, h0 - n, n);
            }
            {
                float r = sigm2(dr[1]);
                float z = sigm2(dz[1]);
                float xn = __builtin_fmaf(xt, wihn[1], bihn[1]);
                float v  = __builtin_fmaf(r, dn[1], xn);
                float n  = __builtin_fmaf(-2.0f, __builtin_amdgcn_rcpf(1.0f + fexp2(v)), 1.0f);
                h1 = __builtin_fmaf(z, h1 - n, n);
            }
            {
                float r = sigm2(dr[2]);
                float z = sigm2(dz[2]);
                float xn = __builtin_fmaf(xt, wihn[2], bihn[2]);
                float v  = __builtin_fmaf(r, dn[2], xn);
                float n  = __builtin_fmaf(-2.0f, __builtin_amdgcn_rcpf(1.0f + fexp2(v)), 1.0f);
                h2 = __builtin_fmaf(z, h2 - n, n);
            }
            {
                float r = sigm2(dr[3]);
                float z = sigm2(dz[3]);
                float xn = __builtin_fmaf(xt, wihn[3], bihn[3]);
                float v  = __builtin_fmaf(r, dn[3], xn);
                float n  = __builtin_fmaf(-2.0f, __builtin_amdgcn_rcpf(1.0f + fexp2(v)), 1.0f);
                h3 = __builtin_fmaf(z, h3 - n, n);
            }
            // repack h -> next-step B fragments (hi + residual lo)
            split_frag(h0, h1, h2, h3, bhi, blo);
        }
        if (c + 1 < T_LEN / 16) { xc0 = xn0; xc1 = xn1; xc2 = xn2; xc3 = xn3; }
    }

    // out[be] = sum_j h[j]*fc_w[j] + fc_b ; lane owns rows jD..jD+3 of element e
    float p = h0 * fc_w[jD] + h1 * fc_w[jD + 1] + h2 * fc_w[jD + 2] + h3 * fc_w[jD + 3];
    p += __shfl_xor(p, 16, 64);
    p += __shfl_xor(p, 32, 64);
    if (L < 16) out[be] = p + fc_b[0];
}

} // namespace

extern "C" void kernel_launch(void* const* d_in, const int* in_sizes, int n_in,
                              void* d_out, int out_size, void* d_ws, size_t ws_size,
                              hipStream_t stream) {
    const float* x    = (const float*)d_in[0];
    const float* W_ih = (const float*)d_in[1];
    const float* W_hh = (const float*)d_in[2];
    const float* b_ih = (const float*)d_in[3];
    const float* b_hh = (const float*)d_in[4];
    const float* fc_w = (const float*)d_in[5];
    const float* fc_b = (const float*)d_in[6];
    float* out = (float*)d_out;

    const int B = out_size;               // 8192
    const int blocks = B / 16;            // 16 elements per 64-thread (1-wave) block
    gru_mfma<<<blocks, 64, 0, stream>>>(x, W_ih, W_hh, b_ih, b_hh,
                                        fc_w, fc_b, out, B);
}

// Round 5
// 125.912 us; speedup vs baseline: 1.3533x; 1.1125x over previous
//
#include <hip/hip_runtime.h>

namespace {

constexpr int T_LEN = 512;
constexpr float LOG2E = 1.4426950408889634f;

typedef _Float16 half4 __attribute__((ext_vector_type(4)));
typedef float v4f __attribute__((ext_vector_type(4)));

__device__ __forceinline__ float fexp2(float a) {
#if __has_builtin(__builtin_amdgcn_exp2f)
    return __builtin_amdgcn_exp2f(a);
#else
    return exp2f(a);
#endif
}

__device__ __forceinline__ v4f mfma16h(half4 a, half4 b, v4f c) {
#if __has_builtin(__builtin_amdgcn_mfma_f32_16x16x16f16)
    return __builtin_amdgcn_mfma_f32_16x16x16f16(a, b, c, 0, 0, 0);
#else
    v4f d;
    asm volatile("v_mfma_f32_16x16x16_f16 %0, %1, %2, %3\n\ts_nop 7\n\ts_nop 7"
                 : "=v"(d) : "v"(a), "v"(b), "v"(c));
    return d;
#endif
}

__global__ __launch_bounds__(64) void gru_mfma(
        const float* __restrict__ x,
        const float* __restrict__ W_ih,
        const float* __restrict__ W_hh,
        const float* __restrict__ b_ih,
        const float* __restrict__ b_hh,
        const float* __restrict__ fc_w,
        const float* __restrict__ fc_b,
        float* __restrict__ out, int B) {
    const int L  = threadIdx.x;      // 0..63
    const int e  = L & 15;           // element column (D/B col) AND A row
    const int g  = L >> 4;           // k/row group
    const int jD = g * 4;            // D rows / B k-range owned by this lane
    const int be = blockIdx.x * 16 + e;

    const float sR = -LOG2E;         // sigmoid: r = rcp(1+exp2(-log2e*a))
    const float sN = 2.0f * LOG2E;   // tanh: n = 1-2*rcp(1+exp2(2*log2e*v))

    // ---- A fragments: W_hh rows (gate out j = e; k = jD..jD+3), scaled,
    //      split into f16 hi + f16 residual (covers W to ~2^-22)
    half4 ar_hi, ar_lo, az_hi, az_lo, an_hi, an_lo;
#pragma unroll
    for (int i = 0; i < 4; ++i) {
        float wr = W_hh[(0  + e) * 16 + jD + i] * sR;
        float wz = W_hh[(16 + e) * 16 + jD + i] * sR;
        float wn = W_hh[(32 + e) * 16 + jD + i] * sN;
        _Float16 rh = (_Float16)wr; ar_hi[i] = rh; ar_lo[i] = (_Float16)(wr - (float)rh);
        _Float16 zh = (_Float16)wz; az_hi[i] = zh; az_lo[i] = (_Float16)(wz - (float)zh);
        _Float16 nh = (_Float16)wn; an_hi[i] = nh; an_lo[i] = (_Float16)(wn - (float)nh);
    }

    // ---- per-D-row constants (rows jD+i)
    float wihr[4], wihz[4], wihn[4], biasr[4], biasz[4], bihn[4];
    v4f cn_const;
#pragma unroll
    for (int i = 0; i < 4; ++i) {
        int rj = jD + i;
        wihr[i]  = W_ih[rj]        * sR;
        wihz[i]  = W_ih[16 + rj]   * sR;
        wihn[i]  = W_ih[32 + rj]   * sN;
        biasr[i] = (b_ih[rj]      + b_hh[rj])      * sR;
        biasz[i] = (b_ih[16 + rj] + b_hh[16 + rj]) * sR;
        bihn[i]  = b_ih[32 + rj]   * sN;
        cn_const[i] = b_hh[32 + rj] * sN;
    }

    // ---- x: this lane's element's timeline, 16 steps per chunk (4 x float4)
    const float4* xb = (const float4*)(x + (size_t)be * T_LEN);
    float4 xc0 = xb[0], xc1 = xb[1], xc2 = xb[2], xc3 = xb[3];

    float h0 = 0.f, h1 = 0.f, h2 = 0.f, h3 = 0.f;
    half4 hf; hf[0] = (_Float16)0.f; hf[1] = (_Float16)0.f;
    hf[2] = (_Float16)0.f; hf[3] = (_Float16)0.f;

#pragma unroll 1
    for (int c = 0; c < T_LEN / 16; ++c) {
        float4 xn0, xn1, xn2, xn3;
        if (c + 1 < T_LEN / 16) {
            xn0 = xb[(c + 1) * 4 + 0];
            xn1 = xb[(c + 1) * 4 + 1];
            xn2 = xb[(c + 1) * 4 + 2];
            xn3 = xb[(c + 1) * 4 + 3];
        }
#pragma unroll
        for (int s = 0; s < 16; ++s) {
            float4 q4 = (s < 4) ? xc0 : (s < 8) ? xc1 : (s < 12) ? xc2 : xc3;
            float xt  = ((s & 3) == 0) ? q4.x : ((s & 3) == 1) ? q4.y
                      : ((s & 3) == 2) ? q4.z : q4.w;

            // C-inits (x-projection + biases, pre-scaled)
            v4f cr, cz;
#pragma unroll
            for (int i = 0; i < 4; ++i) {
                cr[i] = __builtin_fmaf(xt, wihr[i], biasr[i]);
                cz[i] = __builtin_fmaf(xt, wihz[i], biasz[i]);
            }
            // 2 MFMAs per gate: (Whi + Wlo) * hf ; 3-wide ILP, 2-deep chains
            v4f dr = mfma16h(ar_hi, hf, cr);
            v4f dz = mfma16h(az_hi, hf, cz);
            v4f dn = mfma16h(an_hi, hf, cn_const);
            dr = mfma16h(ar_lo, hf, dr);
            dz = mfma16h(az_lo, hf, dz);
            dn = mfma16h(an_lo, hf, dn);

            // gates + h update (fp32); r,z share one rcp via product trick
            float hn_[4];
#pragma unroll
            for (int i = 0; i < 4; ++i) {
                float Er = fexp2(dr[i]);
                float Ez = fexp2(dz[i]);
                float pr = 1.0f + Er;
                float pz = 1.0f + Ez;
                float ip = __builtin_amdgcn_rcpf(pr * pz);
                float r  = ip * pz;            // = 1/(1+Er)
                float z  = ip * pr;            // = 1/(1+Ez)
                float xn = __builtin_fmaf(xt, wihn[i], bihn[i]);
                float v  = __builtin_fmaf(r, dn[i], xn);
                float Ev = fexp2(v);
                float n  = __builtin_fmaf(-2.0f, __builtin_amdgcn_rcpf(1.0f + Ev), 1.0f);
                float hcur = (i == 0) ? h0 : (i == 1) ? h1 : (i == 2) ? h2 : h3;
                float t  = hcur - n;
                float hnew = __builtin_fmaf(z, t, n);
                hn_[i] = hnew;
            }
            h0 = hn_[0]; h1 = hn_[1]; h2 = hn_[2]; h3 = hn_[3];
            // repack h -> next-step f16 B fragment (RTN converts)
            hf[0] = (_Float16)h0; hf[1] = (_Float16)h1;
            hf[2] = (_Float16)h2; hf[3] = (_Float16)h3;
        }
        if (c + 1 < T_LEN / 16) { xc0 = xn0; xc1 = xn1; xc2 = xn2; xc3 = xn3; }
    }

    // out[be] = sum_j h[j]*fc_w[j] + fc_b ; lane owns rows jD..jD+3 of element e
    float p = h0 * fc_w[jD] + h1 * fc_w[jD + 1] + h2 * fc_w[jD + 2] + h3 * fc_w[jD + 3];
    p += __shfl_xor(p, 16, 64);
    p += __shfl_xor(p, 32, 64);
    if (L < 16) out[be] = p + fc_b[0];
}

} // namespace

extern "C" void kernel_launch(void* const* d_in, const int* in_sizes, int n_in,
                              void* d_out, int out_size, void* d_ws, size_t ws_size,
                              hipStream_t stream) {
    const float* x    = (const float*)d_in[0];
    const float* W_ih = (const float*)d_in[1];
    const float* W_hh = (const float*)d_in[2];
    const float* b_ih = (const float*)d_in[3];
    const float* b_hh = (const float*)d_in[4];
    const float* fc_w = (const float*)d_in[5];
    const float* fc_b = (const float*)d_in[6];
    float* out = (float*)d_out;

    const int B = out_size;               // 8192
    const int blocks = B / 16;            // 16 elements per 64-thread (1-wave) block
    gru_mfma<<<blocks, 64, 0, stream>>>(x, W_ih, W_hh, b_ih, b_hh,
                                        fc_w, fc_b, out, B);
}